// Round 2
// baseline (303.222 us; speedup 1.0000x reference)
//
#include <hip/hip_runtime.h>
#include <hip/hip_cooperative_groups.h>
#include <stdint.h>

#define D      10000
#define WPR    313        // ceil(10000/32) words per hypervector row
#define NPIX   784
#define NB     64
#define NC     10
#define TOTW   (1040 * WPR)   // 325520 words to pack (256 lev + 784 pos rows)

namespace cg = cooperative_groups;

// ---------------- fallback path (identical to verified round-1 kernels) ----------------

__global__ __launch_bounds__(320) void pack_kernel(const float* __restrict__ lev,
                                                   const float* __restrict__ pos,
                                                   uint32_t* __restrict__ Lp,
                                                   uint32_t* __restrict__ Pp,
                                                   float* __restrict__ out) {
    if (blockIdx.x == 0)
        for (int i = threadIdx.x; i < NB * NC; i += 320) out[i] = 0.0f;

    int row = blockIdx.x;             // 0..1039
    const float* src; uint32_t* dst;
    if (row < 256) { src = lev + (size_t)row * D;        dst = Lp + row * WPR; }
    else           { src = pos + (size_t)(row - 256) * D; dst = Pp + (row - 256) * WPR; }

    int w = threadIdx.x;
    if (w >= WPR) return;
    const uint4* p4 = (const uint4*)((const uint32_t*)src + w * 32);
    uint32_t word = 0;
    if (w < WPR - 1) {
        #pragma unroll
        for (int k = 0; k < 8; ++k) {
            uint4 u = p4[k];
            word |= (u.x >> 31) << (4 * k)     | (u.y >> 31) << (4 * k + 1)
                  | (u.z >> 31) << (4 * k + 2) | (u.w >> 31) << (4 * k + 3);
        }
    } else {
        #pragma unroll
        for (int k = 0; k < 4; ++k) {
            uint4 u = p4[k];
            word |= (u.x >> 31) << (4 * k)     | (u.y >> 31) << (4 * k + 1)
                  | (u.z >> 31) << (4 * k + 2) | (u.w >> 31) << (4 * k + 3);
        }
    }
    dst[w] = word;
}

__global__ __launch_bounds__(512) void fused_kernel(const float* __restrict__ x,
                                                    const uint32_t* __restrict__ Lp,
                                                    const uint32_t* __restrict__ Pp,
                                                    const float* __restrict__ cw,
                                                    float* __restrict__ out) {
    int tid = threadIdx.x;
    int b = blockIdx.y;
    int bx = blockIdx.x;
    int t = tid >> 6, lane = tid & 63;
    int w32 = lane & 31, h = lane >> 5;
    int w = bx * 32 + w32;
    int wc = w < WPR ? w : WPR - 1;

    __shared__ int idxs[NPIX];
    __shared__ uint32_t part[16][8][36];
    __shared__ float red[8][NC];

    for (int i = tid; i < NPIX; i += 512) {
        float xv = x[b * NPIX + i];
        int v = (int)rintf(xv * 255.0f);
        v = v < 0 ? 0 : (v > 255 ? 255 : v);
        idxs[i] = v * WPR;
    }
    __syncthreads();

    int cc = 2 * t + h;
    int p0 = cc * 49;
    uint32_t s0 = 0, s1 = 0, s2 = 0, s3 = 0, s4 = 0, s5 = 0;
    const uint32_t* pp = Pp + (size_t)p0 * WPR + wc;
    #pragma unroll 7
    for (int i = 0; i < 49; ++i) {
        int ro = idxs[p0 + i];
        uint32_t c = Lp[ro + wc] ^ pp[(size_t)i * WPR];
        uint32_t tt;
        tt = s0 & c; s0 ^= c; c = tt;
        tt = s1 & c; s1 ^= c; c = tt;
        tt = s2 & c; s2 ^= c; c = tt;
        tt = s3 & c; s3 ^= c; c = tt;
        tt = s4 & c; s4 ^= c; c = tt;
        s5 ^= c;
    }

    #pragma unroll
    for (int q = 0; q < 8; ++q) {
        uint32_t wordv = 0;
        #pragma unroll
        for (int r = 0; r < 4; ++r) {
            int j = q * 4 + r;
            uint32_t cnt = ((s0 >> j) & 1u)        | (((s1 >> j) & 1u) << 1)
                         | (((s2 >> j) & 1u) << 2) | (((s3 >> j) & 1u) << 3)
                         | (((s4 >> j) & 1u) << 4) | (((s5 >> j) & 1u) << 5);
            wordv |= cnt << (8 * r);
        }
        part[cc][q][w32] = wordv;
    }
    __syncthreads();

    float acc[NC];
    #pragma unroll
    for (int c = 0; c < NC; ++c) acc[c] = 0.0f;

    if (tid < 256) {
        int rw = tid >> 3, q = tid & 7;
        int ww = bx * 32 + rw;
        int d0 = ww * 32 + q * 4;
        if (ww < WPR && d0 + 3 < D) {
            uint32_t se = 0, so = 0;
            #pragma unroll
            for (int k = 0; k < 16; ++k) {
                uint32_t u = part[k][q][rw];
                se += u & 0x00FF00FFu;
                so += (u >> 8) & 0x00FF00FFu;
            }
            int c0 = se & 0xFFFFu, c1 = so & 0xFFFFu;
            int c2 = se >> 16,     c3 = so >> 16;
            float e0 = (2 * c0 < NPIX) ? 1.0f : -1.0f;
            float e1 = (2 * c1 < NPIX) ? 1.0f : -1.0f;
            float e2 = (2 * c2 < NPIX) ? 1.0f : -1.0f;
            float e3 = (2 * c3 < NPIX) ? 1.0f : -1.0f;
            #pragma unroll
            for (int c = 0; c < NC; ++c) {
                const float4 v = *(const float4*)(cw + (size_t)c * D + d0);
                acc[c] = fmaf(e0, v.x, fmaf(e1, v.y, fmaf(e2, v.z, fmaf(e3, v.w, acc[c]))));
            }
        }
    }

    #pragma unroll
    for (int c = 0; c < NC; ++c) {
        float v = acc[c];
        #pragma unroll
        for (int off = 32; off > 0; off >>= 1) v += __shfl_down(v, off, 64);
        if (lane == 0) red[t][c] = v;
    }
    __syncthreads();
    if (tid < NC) {
        float s = red[0][tid];
        #pragma unroll
        for (int t2 = 1; t2 < 8; ++t2) s += red[t2][tid];
        atomicAdd(&out[b * NC + tid], s);
    }
}

// ---------------- cooperative mega-kernel: pack -> grid.sync -> count+logits ----------------
// Phase 1: one thread per packed word (327,680 threads >= 325,520 words); each thread
// consumes exactly one 128-B line of lev/pos (same access pattern as pack_kernel).
// grid.sync() replaces the kernel boundary (saves a launch + device drain).
// Phase 2: byte-identical to fused_kernel with bx = blockIdx.x>>6, b = blockIdx.x&63.
// __launch_bounds__(512, 6): 6 waves/EU => 3 blocks/CU => all 640 blocks co-resident.
__global__ __launch_bounds__(512, 6) void mega_kernel(const float* __restrict__ x,
                                                      const float* __restrict__ lev,
                                                      const float* __restrict__ pos,
                                                      const float* __restrict__ cw,
                                                      uint32_t* __restrict__ Lp,
                                                      uint32_t* __restrict__ Pp,
                                                      float* __restrict__ out) {
    int tid = threadIdx.x;

    // ---- phase 1: sign-pack lev/pos ----
    if (blockIdx.x == 0)
        for (int i = tid; i < NB * NC; i += 512) out[i] = 0.0f;

    unsigned gtid = blockIdx.x * 512u + (unsigned)tid;
    if (gtid < TOTW) {
        unsigned row = gtid / WPR;            // magic-mul division, once per thread
        int w = (int)(gtid - row * WPR);
        const float* src; uint32_t* dst;
        if (row < 256) { src = lev + (size_t)row * D;         dst = Lp + row * WPR; }
        else           { src = pos + (size_t)(row - 256) * D; dst = Pp + (row - 256) * WPR; }
        const uint4* p4 = (const uint4*)((const uint32_t*)src + w * 32);
        uint32_t word = 0;
        if (w < WPR - 1) {
            #pragma unroll
            for (int k = 0; k < 8; ++k) {
                uint4 u = p4[k];
                word |= (u.x >> 31) << (4 * k)     | (u.y >> 31) << (4 * k + 1)
                      | (u.z >> 31) << (4 * k + 2) | (u.w >> 31) << (4 * k + 3);
            }
        } else {                               // last word: only 16 valid elements
            #pragma unroll
            for (int k = 0; k < 4; ++k) {
                uint4 u = p4[k];
                word |= (u.x >> 31) << (4 * k)     | (u.y >> 31) << (4 * k + 1)
                      | (u.z >> 31) << (4 * k + 2) | (u.w >> 31) << (4 * k + 3);
            }
        }
        dst[w] = word;
    }

    __threadfence();                           // device-scope visibility across XCDs
    cg::this_grid().sync();

    // ---- phase 2: count + logits (identical to fused_kernel) ----
    int b = blockIdx.x & 63, bx = blockIdx.x >> 6;   // 64 consecutive blocks share a word-tile
    int t = tid >> 6, lane = tid & 63;
    int w32 = lane & 31, h = lane >> 5;
    int w = bx * 32 + w32;
    int wc = w < WPR ? w : WPR - 1;

    __shared__ int idxs[NPIX];
    __shared__ uint32_t part[16][8][36];
    __shared__ float red[8][NC];

    for (int i = tid; i < NPIX; i += 512) {
        float xv = x[b * NPIX + i];
        int v = (int)rintf(xv * 255.0f);       // round-half-even == jnp.round
        v = v < 0 ? 0 : (v > 255 ? 255 : v);
        idxs[i] = v * WPR;
    }
    __syncthreads();

    int cc = 2 * t + h;
    int p0 = cc * 49;
    uint32_t s0 = 0, s1 = 0, s2 = 0, s3 = 0, s4 = 0, s5 = 0;
    const uint32_t* pp = Pp + (size_t)p0 * WPR + wc;
    #pragma unroll 7
    for (int i = 0; i < 49; ++i) {
        int ro = idxs[p0 + i];                 // half-wave uniform -> LDS broadcast
        uint32_t c = Lp[ro + wc] ^ pp[(size_t)i * WPR];
        uint32_t tt;
        tt = s0 & c; s0 ^= c; c = tt;
        tt = s1 & c; s1 ^= c; c = tt;
        tt = s2 & c; s2 ^= c; c = tt;
        tt = s3 & c; s3 ^= c; c = tt;
        tt = s4 & c; s4 ^= c; c = tt;
        s5 ^= c;                               // counts <= 49 < 64: no carry-out
    }

    #pragma unroll
    for (int q = 0; q < 8; ++q) {
        uint32_t wordv = 0;
        #pragma unroll
        for (int r = 0; r < 4; ++r) {
            int j = q * 4 + r;
            uint32_t cnt = ((s0 >> j) & 1u)        | (((s1 >> j) & 1u) << 1)
                         | (((s2 >> j) & 1u) << 2) | (((s3 >> j) & 1u) << 3)
                         | (((s4 >> j) & 1u) << 4) | (((s5 >> j) & 1u) << 5);
            wordv |= cnt << (8 * r);
        }
        part[cc][q][w32] = wordv;
    }
    __syncthreads();

    float acc[NC];
    #pragma unroll
    for (int c = 0; c < NC; ++c) acc[c] = 0.0f;

    if (tid < 256) {                           // one thread per (word, quad) = 4 dims
        int rw = tid >> 3, q = tid & 7;
        int ww = bx * 32 + rw;
        int d0 = ww * 32 + q * 4;
        if (ww < WPR && d0 + 3 < D) {
            uint32_t se = 0, so = 0;           // even/odd bytes as 16-bit lanes (<= 784)
            #pragma unroll
            for (int k = 0; k < 16; ++k) {
                uint32_t u = part[k][q][rw];
                se += u & 0x00FF00FFu;
                so += (u >> 8) & 0x00FF00FFu;
            }
            int c0 = se & 0xFFFFu, c1 = so & 0xFFFFu;
            int c2 = se >> 16,     c3 = so >> 16;
            float e0 = (2 * c0 < NPIX) ? 1.0f : -1.0f;
            float e1 = (2 * c1 < NPIX) ? 1.0f : -1.0f;
            float e2 = (2 * c2 < NPIX) ? 1.0f : -1.0f;
            float e3 = (2 * c3 < NPIX) ? 1.0f : -1.0f;
            #pragma unroll
            for (int c = 0; c < NC; ++c) {     // q-fastest -> contiguous float4s
                const float4 v = *(const float4*)(cw + (size_t)c * D + d0);
                acc[c] = fmaf(e0, v.x, fmaf(e1, v.y, fmaf(e2, v.z, fmaf(e3, v.w, acc[c]))));
            }
        }
    }

    #pragma unroll
    for (int c = 0; c < NC; ++c) {
        float v = acc[c];
        #pragma unroll
        for (int off = 32; off > 0; off >>= 1) v += __shfl_down(v, off, 64);
        if (lane == 0) red[t][c] = v;
    }
    __syncthreads();
    if (tid < NC) {
        float s = red[0][tid];
        #pragma unroll
        for (int t2 = 1; t2 < 8; ++t2) s += red[t2][tid];
        atomicAdd(&out[b * NC + tid], s);
    }
}

extern "C" void kernel_launch(void* const* d_in, const int* in_sizes, int n_in,
                              void* d_out, int out_size, void* d_ws, size_t ws_size,
                              hipStream_t stream) {
    const float* x   = (const float*)d_in[0];   // [64, 28, 28]
    const float* pos = (const float*)d_in[1];   // [784, 10000]
    const float* lev = (const float*)d_in[2];   // [256, 10000]
    const float* cw  = (const float*)d_in[3];   // [10, 10000]
    float* out = (float*)d_out;                 // [64, 10] fp32

    uint32_t* Lp = (uint32_t*)d_ws;             // 256*313 words (320 KB)
    uint32_t* Pp = Lp + 256 * WPR;              // 784*313 words (981 KB)

    void* args[] = { (void*)&x, (void*)&lev, (void*)&pos, (void*)&cw,
                     (void*)&Lp, (void*)&Pp, (void*)&out };
    hipError_t err = hipLaunchCooperativeKernel((const void*)mega_kernel,
                                                dim3(640), dim3(512),
                                                args, 0, stream);
    if (err != hipSuccess) {                    // fallback: verified 2-kernel path
        pack_kernel<<<256 + NPIX, 320, 0, stream>>>(lev, pos, Lp, Pp, out);
        dim3 g(10, NB);
        fused_kernel<<<g, 512, 0, stream>>>(x, Lp, Pp, cw, out);
    }
}

// Round 3
// 103.431 us; speedup vs baseline: 2.9316x; 2.9316x over previous
//
#include <hip/hip_runtime.h>
#include <stdint.h>

#define D      10000
#define WPR    313        // ceil(10000/32) words per hypervector row
#define NPIX   784
#define NB     64
#define NC     10

// Pack sign bits of lev [256 x 10000] and pos [784 x 10000] into bitmasks
// (bit=1 <=> value < 0). Thread-per-word: 32 consecutive floats -> 1 uint32,
// via uint4 loads + in-register sign extraction (no cross-lane ops).
// Block 0 additionally zero-inits d_out (so no separate memset dispatch).
// NOTE (R2 lesson): do NOT add a min-waves launch_bounds arg here — capping
// VGPRs serializes the 8 in-flight uint4 loads (VGPR=28 disaster in mega).
__global__ __launch_bounds__(320) void pack_kernel(const float* __restrict__ lev,
                                                   const float* __restrict__ pos,
                                                   uint32_t* __restrict__ Lp,
                                                   uint32_t* __restrict__ Pp,
                                                   float* __restrict__ out) {
    if (blockIdx.x == 0)
        for (int i = threadIdx.x; i < NB * NC; i += 320) out[i] = 0.0f;

    int row = blockIdx.x;             // 0..1039
    const float* src; uint32_t* dst;
    if (row < 256) { src = lev + (size_t)row * D;        dst = Lp + row * WPR; }
    else           { src = pos + (size_t)(row - 256) * D; dst = Pp + (row - 256) * WPR; }

    int w = threadIdx.x;
    if (w >= WPR) return;
    const uint4* p4 = (const uint4*)((const uint32_t*)src + w * 32);
    uint32_t word = 0;
    if (w < WPR - 1) {
        #pragma unroll
        for (int k = 0; k < 8; ++k) {
            uint4 u = p4[k];
            word |= (u.x >> 31) << (4 * k)     | (u.y >> 31) << (4 * k + 1)
                  | (u.z >> 31) << (4 * k + 2) | (u.w >> 31) << (4 * k + 3);
        }
    } else {                           // last word: only 16 valid elements
        #pragma unroll
        for (int k = 0; k < 4; ++k) {
            uint4 u = p4[k];
            word |= (u.x >> 31) << (4 * k)     | (u.y >> 31) << (4 * k + 1)
                  | (u.z >> 31) << (4 * k + 2) | (u.w >> 31) << (4 * k + 3);
        }
    }
    dst[w] = word;
}

// Fused count + logits (verified R1 structure). One block per (32-word tile,
// batch): 8 waves, each lane-half owns one of 16 pixel-chunks (49 px).
// R3 change: phase-A inner loop uses a 3:2 carry-save compressor — 3 pixels
// per iteration through one full-adder (sum/maj), then a single ripple into
// the 6-slice counter. 22 ALU + 6 loads per 3 px vs 42 ALU + 6 loads before.
__global__ __launch_bounds__(512) void fused_kernel(const float* __restrict__ x,
                                                    const uint32_t* __restrict__ Lp,
                                                    const uint32_t* __restrict__ Pp,
                                                    const float* __restrict__ cw,
                                                    float* __restrict__ out) {
    int tid = threadIdx.x;
    int b = blockIdx.y;
    int bx = blockIdx.x;              // 0..9: 32-word tile
    int t = tid >> 6, lane = tid & 63;
    int w32 = lane & 31, h = lane >> 5;
    int w = bx * 32 + w32;            // 0..319
    int wc = w < WPR ? w : WPR - 1;   // clamp: lanes past 313 duplicate word 312

    __shared__ int idxs[NPIX];                 // level-row offsets (pre-mul by WPR)
    __shared__ uint32_t part[16][8][36];       // [chunk][quad][word] byte-packed counts
    __shared__ float red[8][NC];

    for (int i = tid; i < NPIX; i += 512) {
        float xv = x[b * NPIX + i];
        int v = (int)rintf(xv * 255.0f);       // round-half-even == jnp.round
        v = v < 0 ? 0 : (v > 255 ? 255 : v);
        idxs[i] = v * WPR;
    }
    __syncthreads();

    int cc = 2 * t + h;               // chunk 0..15
    int p0 = cc * 49;
    uint32_t s0 = 0, s1 = 0, s2 = 0, s3 = 0, s4 = 0, s5 = 0;
    const uint32_t* pp = Pp + (size_t)p0 * WPR + wc;

    // 49 px = 16 triples + 1 leftover. Full-adder (sum,maj) per triple, then
    // one ripple. Counts <= 49 < 64: s5 never carries out.
    #pragma unroll 4
    for (int i = 0; i < 48; i += 3) {
        uint32_t c0 = Lp[idxs[p0 + i]     + wc] ^ pp[(size_t)(i)     * WPR];
        uint32_t c1 = Lp[idxs[p0 + i + 1] + wc] ^ pp[(size_t)(i + 1) * WPR];
        uint32_t c2 = Lp[idxs[p0 + i + 2] + wc] ^ pp[(size_t)(i + 2) * WPR];
        uint32_t u   = c0 ^ c1;
        uint32_t sum = u ^ c2;                 // weight 1
        uint32_t maj = (c0 & c1) | (u & c2);   // weight 2
        uint32_t t0 = s0 & sum; s0 ^= sum;     // carry t0 (weight 2)
        uint32_t w2  = maj ^ t0;
        uint32_t w2c = maj & t0;               // weight 4
        uint32_t t1 = s1 & w2;  s1 ^= w2;      // t1 (weight 4); t1 & w2c == 0
        uint32_t c4 = t1 | w2c;
        uint32_t t2 = s2 & c4;  s2 ^= c4;
        uint32_t t3 = s3 & t2;  s3 ^= t2;
        uint32_t t4 = s4 & t3;  s4 ^= t3;
        s5 ^= t4;
    }
    {   // leftover pixel 48
        uint32_t c = Lp[idxs[p0 + 48] + wc] ^ pp[(size_t)48 * WPR];
        uint32_t tt;
        tt = s0 & c; s0 ^= c; c = tt;
        tt = s1 & c; s1 ^= c; c = tt;
        tt = s2 & c; s2 ^= c; c = tt;
        tt = s3 & c; s3 ^= c; c = tt;
        tt = s4 & c; s4 ^= c; c = tt;
        s5 ^= c;
    }

    #pragma unroll
    for (int q = 0; q < 8; ++q) {      // byte-pack 4 counts per word into LDS
        uint32_t wordv = 0;
        #pragma unroll
        for (int r = 0; r < 4; ++r) {
            int j = q * 4 + r;
            uint32_t cnt = ((s0 >> j) & 1u)        | (((s1 >> j) & 1u) << 1)
                         | (((s2 >> j) & 1u) << 2) | (((s3 >> j) & 1u) << 3)
                         | (((s4 >> j) & 1u) << 4) | (((s5 >> j) & 1u) << 5);
            wordv |= cnt << (8 * r);
        }
        part[cc][q][w32] = wordv;
    }
    __syncthreads();

    float acc[NC];
    #pragma unroll
    for (int c = 0; c < NC; ++c) acc[c] = 0.0f;

    if (tid < 256) {                   // one thread per (word, quad) = 4 dims
        int rw = tid >> 3, q = tid & 7;
        int ww = bx * 32 + rw;
        int d0 = ww * 32 + q * 4;
        if (ww < WPR && d0 + 3 < D) {
            uint32_t se = 0, so = 0;   // even/odd bytes as 16-bit lanes (<= 784)
            #pragma unroll
            for (int k = 0; k < 16; ++k) {
                uint32_t u = part[k][q][rw];
                se += u & 0x00FF00FFu;
                so += (u >> 8) & 0x00FF00FFu;
            }
            int c0 = se & 0xFFFFu, c1 = so & 0xFFFFu;
            int c2 = se >> 16,     c3 = so >> 16;
            float e0 = (2 * c0 < NPIX) ? 1.0f : -1.0f;
            float e1 = (2 * c1 < NPIX) ? 1.0f : -1.0f;
            float e2 = (2 * c2 < NPIX) ? 1.0f : -1.0f;
            float e3 = (2 * c3 < NPIX) ? 1.0f : -1.0f;
            #pragma unroll
            for (int c = 0; c < NC; ++c) {   // lanes q-fastest -> contiguous float4s
                const float4 v = *(const float4*)(cw + (size_t)c * D + d0);
                acc[c] = fmaf(e0, v.x, fmaf(e1, v.y, fmaf(e2, v.z, fmaf(e3, v.w, acc[c]))));
            }
        }
    }

    #pragma unroll
    for (int c = 0; c < NC; ++c) {
        float v = acc[c];
        #pragma unroll
        for (int off = 32; off > 0; off >>= 1) v += __shfl_down(v, off, 64);
        if (lane == 0) red[t][c] = v;
    }
    __syncthreads();
    if (tid < NC) {
        float s = red[0][tid];
        #pragma unroll
        for (int t2 = 1; t2 < 8; ++t2) s += red[t2][tid];
        atomicAdd(&out[b * NC + tid], s);
    }
}

extern "C" void kernel_launch(void* const* d_in, const int* in_sizes, int n_in,
                              void* d_out, int out_size, void* d_ws, size_t ws_size,
                              hipStream_t stream) {
    const float* x   = (const float*)d_in[0];   // [64, 28, 28]
    const float* pos = (const float*)d_in[1];   // [784, 10000]
    const float* lev = (const float*)d_in[2];   // [256, 10000]
    const float* cw  = (const float*)d_in[3];   // [10, 10000]
    float* out = (float*)d_out;                 // [64, 10] fp32

    uint32_t* Lp = (uint32_t*)d_ws;             // 256*313 words (320 KB)
    uint32_t* Pp = Lp + 256 * WPR;              // 784*313 words (981 KB)

    pack_kernel<<<256 + NPIX, 320, 0, stream>>>(lev, pos, Lp, Pp, out);
    dim3 g(10, NB);                             // 640 blocks: 2.5/CU, 5 waves/SIMD
    fused_kernel<<<g, 512, 0, stream>>>(x, Lp, Pp, cw, out);
}